// Round 7
// baseline (195.905 us; speedup 1.0000x reference)
//
#include <hip/hip_runtime.h>
#include <hip/hip_bf16.h>

#define D 64

typedef float f32x4 __attribute__((ext_vector_type(4)));
typedef float f32x2 __attribute__((ext_vector_type(2)));

// ---- kernel 0: zero counts (int4) ----
__global__ void zero_kernel(int4* __restrict__ p, int n4) {
    int i = blockIdx.x * blockDim.x + threadIdx.x;
    if (i < n4) p[i] = make_int4(0, 0, 0, 0);
}

// ---- kernel 1: histogram counts[dst[e]]++ (int4 reads) ----
__global__ void count_kernel(const int4* __restrict__ dst4, int* __restrict__ counts, int E4) {
    int i = blockIdx.x * blockDim.x + threadIdx.x;
    if (i < E4) {
        int4 d = dst4[i];
        atomicAdd(&counts[d.x], 1);
        atomicAdd(&counts[d.y], 1);
        atomicAdd(&counts[d.z], 1);
        atomicAdd(&counts[d.w], 1);
    }
}

// ---- kernel 2a: per-block sums of counts (256/block) ----
__global__ void blocksum_kernel(const int* __restrict__ counts, int* __restrict__ bsums, int N) {
    int t = threadIdx.x;
    int i = blockIdx.x * 256 + t;
    int v = (i < N) ? counts[i] : 0;
    int lane = t & 63, wave = t >> 6;
    #pragma unroll
    for (int o = 1; o < 64; o <<= 1) v += __shfl_xor(v, o);
    __shared__ int ws[4];
    if (lane == 0) ws[wave] = v;
    __syncthreads();
    if (t == 0) bsums[blockIdx.x] = ws[0] + ws[1] + ws[2] + ws[3];
}

// ---- kernel 2b: single-block scan of block sums + fused Wc/bc combine (LDS-staged) ----
__global__ void blockscan_kernel(const int* __restrict__ bsums, int* __restrict__ boffs,
                                 int* __restrict__ offsets, int N, int nb,
                                 const float* __restrict__ Wp, const float* __restrict__ Wu,
                                 const float* __restrict__ bp,
                                 float* __restrict__ Wc, float* __restrict__ bc) {
    __shared__ int wsum[16];
    __shared__ float wu[D * D];
    __shared__ float wp[D * D];
    int t = threadIdx.x;
    for (int i = t; i < D * D; i += 1024) { wu[i] = Wu[i]; wp[i] = Wp[i]; }

    int wave = t >> 6, lane = t & 63;
    int v = (t < nb) ? bsums[t] : 0;
    int s = v;
    #pragma unroll
    for (int off = 1; off < 64; off <<= 1) {
        int x = __shfl_up(s, off);
        if (lane >= off) s += x;
    }
    if (lane == 63) wsum[wave] = s;
    __syncthreads();
    int wbase = 0, total = 0;
    #pragma unroll
    for (int w = 0; w < 16; ++w) {
        int x = wsum[w];
        total += x;
        if (w < wave) wbase += x;
    }
    if (t < nb) boffs[t] = s - v + wbase;
    if (t == 0) offsets[N] = total;   // == E

    for (int idx = t; idx < D * D; idx += 1024) {
        int d = idx >> 6, j = idx & 63;
        float acc = 0.f;
        #pragma unroll
        for (int k = 0; k < D; ++k) acc = fmaf(wp[d * D + k], wu[k * D + j], acc);
        Wc[idx] = acc;
    }
    if (t < D) {
        float acc = 0.f;
        #pragma unroll
        for (int k = 0; k < D; ++k) acc = fmaf(bp[k], wu[k * D + t], acc);
        bc[t] = acc;
    }
}

// ---- kernel 2c: per-block exclusive scan + block offset -> offsets, cursor ----
__global__ void scatter_scan_kernel(const int* __restrict__ counts, const int* __restrict__ boffs,
                                    int* __restrict__ offsets, int* __restrict__ cursor, int N) {
    int t = threadIdx.x;
    int i = blockIdx.x * 256 + t;
    int v = (i < N) ? counts[i] : 0;
    int lane = t & 63, wave = t >> 6;
    int s = v;
    #pragma unroll
    for (int off = 1; off < 64; off <<= 1) {
        int x = __shfl_up(s, off);
        if (lane >= off) s += x;
    }
    __shared__ int ws[4];
    if (lane == 63) ws[wave] = s;
    __syncthreads();
    int wbase = 0;
    #pragma unroll
    for (int w = 0; w < 4; ++w) if (w < wave) wbase += ws[w];
    int excl = s - v + wbase + boffs[blockIdx.x];
    if (i < N) { offsets[i] = excl; cursor[i] = excl; }
}

// ---- kernel 3: fused fill+convert+scatter: stream f32 rows, write bf16 rows to CSR slots ----
// thread t -> (edge e = t>>5, chunk j = t&31). Wave = 2 edges: lanes 0-31 edge A, 32-63 edge B.
// Reads: 64 lanes x 8B = 512B contiguous. Writes: two random full 128B lines.
__global__ __launch_bounds__(256) void scatter_bf16_kernel(
        const f32x2* __restrict__ attrs2, const int* __restrict__ dst,
        int* __restrict__ cursor, ushort2* __restrict__ ebuf, int E) {
    int lane = threadIdx.x & 63;
    int stride = gridDim.x * 256;
    int E32 = E * 32;
    for (int t = blockIdx.x * 256 + threadIdx.x; t < E32; t += stride) {
        int e = t >> 5, j = t & 31;
        f32x2 v = __builtin_nontemporal_load(&attrs2[t]);   // == attrs2[e*32 + j]
        int pos = 0;
        if ((lane & 31) == 0) pos = atomicAdd(&cursor[dst[e]], 1);
        pos = __shfl(pos, lane & 32);
        // f32 -> bf16 RNE
        unsigned ux = __float_as_uint(v.x);
        unsigned uy = __float_as_uint(v.y);
        ux = (ux + 0x7fffu + ((ux >> 16) & 1u)) >> 16;
        uy = (uy + 0x7fffu + ((uy >> 16) & 1u)) >> 16;
        ebuf[(size_t)pos * 32 + j] = make_ushort2((unsigned short)ux, (unsigned short)uy);
    }
}

// ---- kernel 4: per-node streaming consume (bf16 rows, contiguous) + mean + fused matmul ----
__global__ __launch_bounds__(256) void node_kernel(
        const f32x4* __restrict__ ebuf4,   // bf16 buffer; row r = 8 x 16B chunks at r*8
        const int* __restrict__ offsets,
        const float* __restrict__ Wc, const float* __restrict__ bc,
        const float* __restrict__ ub, float* __restrict__ out, int N) {
    __shared__ float wlds[D * D];
    __shared__ float blds[D];
    __shared__ float ulds[D];
    __shared__ int soff[5];
    int t = threadIdx.x;
    int nbase = blockIdx.x * 4;
    if (t < 5) {
        int nn = nbase + t;
        soff[t] = offsets[(nn <= N) ? nn : N];
    }
    #pragma unroll
    for (int i = t; i < D * D; i += 256) wlds[i] = Wc[i];
    if (t < D) { blds[t] = bc[t]; ulds[t] = ub[t]; }
    __syncthreads();

    int wave = t >> 6, lane = t & 63;
    int n = nbase + wave;
    if (n >= N) return;

    int off = soff[wave];
    int off2 = soff[wave + 1];
    int cnt = off2 - off;

    int rsel = lane >> 3;   // row-in-window 0..7
    int csel = lane & 7;    // 16B chunk within row (8 bf16 elems)

    float a0 = 0.f, a1 = 0.f, a2 = 0.f, a3 = 0.f, a4 = 0.f, a5 = 0.f, a6 = 0.f, a7 = 0.f;
    // window of 8 rows: 64 lanes x 16B = 1KB contiguous
    for (int r0 = off; r0 < off2; r0 += 8) {
        int row = r0 + rsel;
        bool valid = row < off2;
        int idx = (valid ? row : off) * 8 + csel;
        f32x4 c = ebuf4[idx];
        if (valid) {
            unsigned u0 = __float_as_uint(c.x), u1 = __float_as_uint(c.y);
            unsigned u2 = __float_as_uint(c.z), u3 = __float_as_uint(c.w);
            a0 += __uint_as_float(u0 << 16); a1 += __uint_as_float(u0 & 0xffff0000u);
            a2 += __uint_as_float(u1 << 16); a3 += __uint_as_float(u1 & 0xffff0000u);
            a4 += __uint_as_float(u2 << 16); a5 += __uint_as_float(u2 & 0xffff0000u);
            a6 += __uint_as_float(u3 << 16); a7 += __uint_as_float(u3 & 0xffff0000u);
        }
    }
    // reduce across the 8 row-slots (lanes differing in bits 3,4,5)
    #pragma unroll
    for (int mask = 8; mask < 64; mask <<= 1) {
        a0 += __shfl_xor(a0, mask); a1 += __shfl_xor(a1, mask);
        a2 += __shfl_xor(a2, mask); a3 += __shfl_xor(a3, mask);
        a4 += __shfl_xor(a4, mask); a5 += __shfl_xor(a5, mask);
        a6 += __shfl_xor(a6, mask); a7 += __shfl_xor(a7, mask);
    }
    float inv = (cnt > 0) ? 1.f / (float)cnt : 0.f;
    float marr[8] = { a0 * inv, a1 * inv, a2 * inv, a3 * inv,
                      a4 * inv, a5 * inv, a6 * inv, a7 * inv };
    // lane l holds dims [(l&7)*8 + k], k=0..7 -> mean[d] lives in lane (d>>3), slot (d&7)

    float accO = ulds[lane] + ((cnt > 0) ? blds[lane] : 0.f);
    #pragma unroll
    for (int d = 0; d < D; ++d) {
        float mv = __shfl(marr[d & 7], d >> 3);
        accO = fmaf(mv, wlds[d * D + lane], accO);
    }
    out[(size_t)n * D + lane] = accO;
}

extern "C" void kernel_launch(void* const* d_in, const int* in_sizes, int n_in,
                              void* d_out, int out_size, void* d_ws, size_t ws_size,
                              hipStream_t stream) {
    const float* edge_attrs = (const float*)d_in[0];
    const float* proj_W     = (const float*)d_in[1];
    const float* proj_b     = (const float*)d_in[2];
    const float* upd_W      = (const float*)d_in[3];
    const float* upd_b      = (const float*)d_in[4];
    const int*   dst        = (const int*)d_in[5];

    const int E = in_sizes[0] / D;
    const int N = out_size / D;
    const int nb = (N + 255) / 256;   // 196 for N=50000
    const int E4 = E / 4;
    const int N4 = N / 4;

    // ws layout
    int*   counts  = (int*)d_ws;
    int*   offsets = counts + N;          // N+1 entries
    int*   cursor  = offsets + N + 1;
    int*   bsums   = cursor + N;
    int*   boffs   = bsums + nb;
    float* Wc      = (float*)(boffs + nb);
    float* bc      = Wc + D * D;
    // align bf16 edge buffer to 256B
    size_t ebuf_off = (((size_t)(bc + D) - (size_t)d_ws) + 255) & ~(size_t)255;
    ushort2* ebuf   = (ushort2*)((char*)d_ws + ebuf_off);   // E rows x 128B

    zero_kernel<<<(N4 + 255) / 256, 256, 0, stream>>>((int4*)counts, N4);
    count_kernel<<<(E4 + 255) / 256, 256, 0, stream>>>((const int4*)dst, counts, E4);
    blocksum_kernel<<<nb, 256, 0, stream>>>(counts, bsums, N);
    blockscan_kernel<<<1, 1024, 0, stream>>>(bsums, boffs, offsets, N, nb,
                                             proj_W, upd_W, proj_b, Wc, bc);
    scatter_scan_kernel<<<nb, 256, 0, stream>>>(counts, boffs, offsets, cursor, N);
    scatter_bf16_kernel<<<2048, 256, 0, stream>>>((const f32x2*)edge_attrs, dst,
                                                  cursor, ebuf, E);

    int blocks_n = (N + 3) / 4;
    node_kernel<<<blocks_n, 256, 0, stream>>>((const f32x4*)ebuf, offsets,
                                              Wc, bc, upd_b, (float*)d_out, N);
}